// Round 16
// baseline (274.230 us; speedup 1.0000x reference)
//
#include <hip/hip_runtime.h>
#include <hip/hip_fp16.h>
#include <stdint.h>

// ---------------------------------------------------------------------------
// GCN 3-layer forward, MI355X. Round 16 (= r14 + fixes):
//  - PRNG placement reverted to r14 (best measured): mask1 ballots in k_agg_x,
//    inline threefry in k_agg_w. (r15's GEMM-epilogue placement re-exposed the
//    serial chain at 2 waves/SIMD: GEMM-1 45.5us, VALUBusy 53%.)
//  - drop_keep in exact integer form (r15, bit-identical): bits < 0xCCCCCE00.
//  - agg gather loops: 16-wide main + 4-wide mid + scalar tail (was 8+scalar;
//    deg~Poisson(16) => old scalar tail averaged ~4 serial 500cy gathers/node).
// ---------------------------------------------------------------------------

typedef __attribute__((ext_vector_type(8))) short s8v;   // 8 f16 (4 VGPR)
typedef __attribute__((ext_vector_type(4))) float f4v;   // 4 f32 acc

__device__ __host__ __forceinline__ uint32_t tf_rotl(uint32_t v, int r) {
  return (v << r) | (v >> (32 - r));
}

__device__ __host__ __forceinline__ void threefry2x32(uint32_t k0, uint32_t k1,
                                                      uint32_t x0, uint32_t x1,
                                                      uint32_t& o0, uint32_t& o1) {
  const uint32_t k2 = k0 ^ k1 ^ 0x1BD11BDAu;
  x0 += k0; x1 += k1;
#define TFR(r) { x0 += x1; x1 = tf_rotl(x1, r); x1 ^= x0; }
  TFR(13) TFR(15) TFR(26) TFR(6)
  x0 += k1; x1 += k2 + 1u;
  TFR(17) TFR(29) TFR(16) TFR(24)
  x0 += k2; x1 += k0 + 2u;
  TFR(13) TFR(15) TFR(26) TFR(6)
  x0 += k0; x1 += k1 + 3u;
  TFR(17) TFR(29) TFR(16) TFR(24)
  x0 += k1; x1 += k2 + 4u;
  TFR(13) TFR(15) TFR(26) TFR(6)
  x0 += k2; x1 += k0 + 5u;
#undef TFR
  o0 = x0; o1 = x1;
}

// keep <=> uniform(bits) < 0.8 ; exact integer form (boundary-verified):
// u = bitcast(0x3f800000|(bits>>9)) - 1 < 0.8f  <=>  bits < 0xCCCCCE00
__device__ __forceinline__ bool drop_keep(uint32_t k0, uint32_t k1, uint32_t j) {
  uint32_t a, b;
  threefry2x32(k0, k1, 0u, j, a, b);
  return (a ^ b) < 0xCCCCCE00u;
}

// f16 hi / scaled-lo helper (weights only)
__device__ __forceinline__ void split16(float v, uint16_t& h, uint16_t& l) {
  __half hh = __float2half_rn(v);
  h = __half_as_ushort(hh);
  l = __half_as_ushort(__float2half_rn((v - __half2float(hh)) * 2048.0f));
}

// async global->LDS, 16B/lane; lds base wave-uniform (HW adds lane*16)
__device__ __forceinline__ void gll16(const void* g, void* l) {
  __builtin_amdgcn_global_load_lds(
      (const __attribute__((address_space(1))) uint32_t*)g,
      (__attribute__((address_space(3))) uint32_t*)l, 16, 0, 0);
}

// ------------------------- CSR build -------------------------
__global__ void k_hist(const int* __restrict__ tgt, int* __restrict__ cnt, int E) {
  int e = blockIdx.x * 256 + threadIdx.x;
  if (e < E) atomicAdd(&cnt[tgt[e]], 1);
}

__global__ __launch_bounds__(256) void k_scan1(const int* __restrict__ cnt,
                                               int* __restrict__ row_start,
                                               int* __restrict__ bsum,
                                               float* __restrict__ dinv, int n) {
  int tid = threadIdx.x;
  int i = blockIdx.x * 256 + tid;
  int c = (i < n) ? cnt[i] : 0;
  if (i < n) dinv[i] = rsqrtf((float)(c + 1));  // +1 self-loop
  int lane = tid & 63, wv = tid >> 6;
  int v = c;
#pragma unroll
  for (int d = 1; d < 64; d <<= 1) {
    int u = __shfl_up(v, d);
    if (lane >= d) v += u;
  }
  __shared__ int ws[4];
  if (lane == 63) ws[wv] = v;
  __syncthreads();
  int add = 0;
#pragma unroll
  for (int w = 0; w < 4; ++w)
    if (w < wv) add += ws[w];
  int incl = v + add;
  if (i < n) row_start[i] = incl - c;
  if (tid == 255) bsum[blockIdx.x] = incl;
}

__global__ __launch_bounds__(256) void k_scan2(const int* __restrict__ bsum,
                                               int* __restrict__ bbase,
                                               int* __restrict__ row_start,
                                               int nb, int n) {
  int tid = threadIdx.x;
  int c = (tid < nb) ? bsum[tid] : 0;
  int lane = tid & 63, wv = tid >> 6;
  int v = c;
#pragma unroll
  for (int d = 1; d < 64; d <<= 1) {
    int u = __shfl_up(v, d);
    if (lane >= d) v += u;
  }
  __shared__ int ws[4];
  if (lane == 63) ws[wv] = v;
  __syncthreads();
  int add = 0;
#pragma unroll
  for (int w = 0; w < 4; ++w)
    if (w < wv) add += ws[w];
  int incl = v + add;
  if (tid < nb) bbase[tid] = incl - c;
  if (tid == 255) row_start[n] = incl;
}

__global__ void k_scan3(int* __restrict__ row_start, const int* __restrict__ bbase, int n) {
  int i = blockIdx.x * 256 + threadIdx.x;
  if (i < n) row_start[i] += bbase[blockIdx.x];
}

__global__ void k_scatter(const int* __restrict__ src, const int* __restrict__ tgt,
                          const int* __restrict__ row_start, int* __restrict__ cursor,
                          int* __restrict__ csr_src, int E) {
  int e = blockIdx.x * 256 + threadIdx.x;
  if (e >= E) return;
  int t = tgt[e];
  int pos = atomicAdd(&cursor[t], 1);
  csr_src[row_start[t] + pos] = src[e];
}

// ------------------------- fused weight transpose + f16 hi/lo' split --------------
__global__ void k_cvtW3(const float* __restrict__ W1, uint16_t* __restrict__ W1h,
                        uint16_t* __restrict__ W1l,
                        const float* __restrict__ W2, uint16_t* __restrict__ W2h,
                        uint16_t* __restrict__ W2l,
                        const float* __restrict__ W3, uint16_t* __restrict__ W3h,
                        uint16_t* __restrict__ W3l) {
  const int T1 = 256 * 128, T2 = 128 * 256, T3 = 64 * 128;
  int i = blockIdx.x * 256 + threadIdx.x;
  if (i < T1) {
    int nn = i >> 7, kk = i & 127;                  // K=128, N=256
    split16(W1[(size_t)kk * 256 + nn], W1h[i], W1l[i]);
  } else if (i < T1 + T2) {
    int j = i - T1;
    int nn = j >> 8, kk = j & 255;                  // K=256, N=128
    split16(W2[(size_t)kk * 128 + nn], W2h[j], W2l[j]);
  } else if (i < T1 + T2 + T3) {
    int j = i - T1 - T2;
    int nn = j >> 7, kk = j & 127;                  // K=128, N=64
    split16(W3[(size_t)kk * 64 + nn], W3h[j], W3l[j]);
  }
}

// ------------------------- xs16 = f16(x * dinv[row]) -------------------------
__global__ void k_scale16(const float* __restrict__ x, const float* __restrict__ dinv,
                          uint16_t* __restrict__ xs, int total2) {
  int i = blockIdx.x * 256 + threadIdx.x;
  if (i >= total2) return;
  float2 v = ((const float2*)x)[i];
  float s = dinv[i >> 6];
  __half2 h;
  h.x = __float2half_rn(v.x * s);
  h.y = __float2half_rn(v.y * s);
  ((__half2*)xs)[i] = h;
}

// ------------------------- f16 MFMA GEMM, barrier-free, XCD-swizzled grid --------
// 1-D grid: xcd=id&7, ct=(id>>3)%CTN, rb=((id>>3)/CTN)*8+xcd (rb>=RB -> exit).
// Block: 4 waves, 128 rows x 64 cols. B tile (64 cols x K, hi+lo') in LDS once;
// A fragments (single f16) global->reg once. 2 MFMA passes: Ah*Bh, Ah*Bl.
// MODE 0: C16=f16(v*sb[row]);  MODE 1: Cf=v+sb[col];  MODE 2: C16=f16(relu(mask?v*1.25:0))
template <int MODE, int K>
__global__ __launch_bounds__(256, K == 128 ? 4 : 2) void k_mfma(
    const uint16_t* __restrict__ Ah,
    const uint16_t* __restrict__ Bh, const uint16_t* __restrict__ Bl,
    const float* __restrict__ sb, float* __restrict__ Cf,
    uint16_t* __restrict__ C16, const uint64_t* __restrict__ mask,
    int M, int N, int CTN, int RB) {
  constexpr int SEGS = K / 8;
  constexpr int CHT = 64 * SEGS;         // 16B chunks per B array
  constexpr int KS = K / 32;
  extern __shared__ uint16_t lB[];       // hi CHT*8, lo CHT*8

  int id = blockIdx.x;
  int xcd = id & 7;
  int q = id >> 3;
  int ct = q % CTN;
  int rb = (q / CTN) * 8 + xcd;
  if (rb >= RB) return;

  int tid = threadIdx.x;
  int lane = tid & 63;
  int wid = tid >> 6;
  int r16 = lane & 15, kq = lane >> 4;
  int bm = rb * 128, bn0 = ct * 64;

  // ---- stage B tile (hi + lo') once ----
#pragma unroll
  for (int p = 0; p < (2 * CHT) / 256; ++p) {
    int c = p * 256 + tid;
    int arr = (c >= CHT);
    int cc = arr ? c - CHT : c;
    int row = cc / SEGS, u = cc - row * SEGS;
    int seg = u ^ (row & 7);  // inverse-swizzled source
    const uint16_t* src = (arr ? Bl : Bh) + (size_t)(bn0 + row) * K + seg * 8;
    gll16(src, lB + (size_t)(p * 256 + (wid << 6)) * 8);
  }

  // ---- load A fragments once (overlaps B staging latency) ----
  int mrow0 = bm + wid * 32;
  s8v aH[2][KS];
#pragma unroll
  for (int mb = 0; mb < 2; ++mb)
#pragma unroll
    for (int ks = 0; ks < KS; ++ks) {
      size_t ga = (size_t)(mrow0 + mb * 16 + r16) * K + ks * 32 + kq * 8;
      aH[mb][ks] = *(const s8v*)&Ah[ga];
    }

  asm volatile("s_waitcnt vmcnt(0)" ::: "memory");
  __syncthreads();

  const uint16_t* tbh = lB;
  const uint16_t* tbl = lB + (size_t)CHT * 8;
  f4v accH[2][4] = {};
  f4v accL[2][4] = {};
#pragma unroll
  for (int ks = 0; ks < KS; ++ks) {
    s8v bh[4], bl[4];
#pragma unroll
    for (int nb = 0; nb < 4; ++nb) {
      int brow = nb * 16 + r16;
      int u = (ks * 4 + kq) ^ (brow & 7);
      bh[nb] = *(const s8v*)&tbh[brow * K + u * 8];
      bl[nb] = *(const s8v*)&tbl[brow * K + u * 8];
    }
#pragma unroll
    for (int mb = 0; mb < 2; ++mb) {
#pragma unroll
      for (int nb = 0; nb < 4; ++nb) {
        accH[mb][nb] = __builtin_amdgcn_mfma_f32_16x16x32_f16(aH[mb][ks], bh[nb], accH[mb][nb], 0, 0, 0);
        accL[mb][nb] = __builtin_amdgcn_mfma_f32_16x16x32_f16(aH[mb][ks], bl[nb], accL[mb][nb], 0, 0, 0);
      }
    }
  }

  // ---- epilogue ----
#pragma unroll
  for (int mb = 0; mb < 2; ++mb) {
#pragma unroll
    for (int nb = 0; nb < 4; ++nb) {
      int col = bn0 + nb * 16 + r16;
#pragma unroll
      for (int r = 0; r < 4; ++r) {
        int row = mrow0 + mb * 16 + kq * 4 + r;
        if (row >= M) continue;
        float v = accH[mb][nb][r] + accL[mb][nb][r] * (1.0f / 2048.0f);
        size_t o = (size_t)row * N + col;
        if (MODE == 0) {
          C16[o] = __half_as_ushort(__float2half_rn(v * sb[row]));
        } else if (MODE == 1) {
          Cf[o] = v + sb[col];
        } else {
          v += sb[col];
          uint64_t m = mask[(size_t)row * (N >> 6) + (col >> 6)];
          v = ((m >> (col & 63)) & 1ull) ? fmaxf(v * 1.25f, 0.f) : 0.f;
          C16[o] = __half_as_ushort(__float2half_rn(v));
        }
      }
    }
  }
}

// ------------------------- layer-1 aggregation (MLP 16/4/1) + mask1 ballots -------
__global__ __launch_bounds__(256) void k_agg_x(const uint16_t* __restrict__ xs,
                                               const float* __restrict__ dinv,
                                               const int* __restrict__ row_start,
                                               const int* __restrict__ csr_src,
                                               uint32_t* __restrict__ out,
                                               uint64_t* __restrict__ mask1,
                                               uint32_t k0, uint32_t k1, int n) {
  const int F = 128;
  int wid = (int)((blockIdx.x * 256 + threadIdx.x) >> 6);
  if (wid >= n) return;
  int lane = threadIdx.x & 63;
  int t = wid;
  float2 a[16];
  a[0] = __half22float2(((const __half2*)(xs + (size_t)t * F))[lane]);
#pragma unroll
  for (int q = 1; q < 16; ++q) a[q] = make_float2(0.f, 0.f);
  int e0 = row_start[t], e1 = row_start[t + 1];
  int e = e0;
  for (; e + 16 <= e1; e += 16) {
#pragma unroll
    for (int q = 0; q < 16; ++q) {
      int s = csr_src[e + q];
      float2 v = __half22float2(((const __half2*)(xs + (size_t)s * F))[lane]);
      a[q].x += v.x;
      a[q].y += v.y;
    }
  }
  for (; e + 4 <= e1; e += 4) {
#pragma unroll
    for (int q = 0; q < 4; ++q) {
      int s = csr_src[e + q];
      float2 v = __half22float2(((const __half2*)(xs + (size_t)s * F))[lane]);
      a[q].x += v.x;
      a[q].y += v.y;
    }
  }
  for (; e < e1; ++e) {
    int s = csr_src[e];
    float2 v = __half22float2(((const __half2*)(xs + (size_t)s * F))[lane]);
    a[0].x += v.x; a[0].y += v.y;
  }
#pragma unroll
  for (int q = 0; q < 8; ++q) {
    a[q].x += a[q + 8].x;
    a[q].y += a[q + 8].y;
  }
  float dt = dinv[t];
  float rx = (((a[0].x + a[1].x) + (a[2].x + a[3].x)) + ((a[4].x + a[5].x) + (a[6].x + a[7].x))) * dt;
  float ry = (((a[0].y + a[1].y) + (a[2].y + a[3].y)) + ((a[4].y + a[5].y) + (a[6].y + a[7].y))) * dt;
  __half2 o;
  o.x = __float2half_rn(rx);
  o.y = __float2half_rn(ry);
  out[(size_t)t * 64 + lane] = *(uint32_t*)&o;
  // layer-1 dropout mask (hidden under gather latency): elem j = t*256 + w*64 + lane
#pragma unroll
  for (int w = 0; w < 4; ++w) {
    bool kp = drop_keep(k0, k1, (uint32_t)t * 256u + (uint32_t)(w * 64 + lane));
    uint64_t m = __ballot(kp);
    if (lane == 0) mask1[(size_t)t * 4 + w] = m;
  }
}

// ------------------------- layer-2 aggregation + bias + inline-drop + relu --------
__global__ __launch_bounds__(256) void k_agg_w(const uint16_t* __restrict__ hws,
                                               const float* __restrict__ dinv,
                                               const float* __restrict__ bias,
                                               const int* __restrict__ row_start,
                                               const int* __restrict__ csr_src,
                                               uint32_t* __restrict__ out,
                                               uint32_t k0, uint32_t k1, int n) {
  const int F = 128;
  int wid = (int)((blockIdx.x * 256 + threadIdx.x) >> 6);
  if (wid >= n) return;
  int lane = threadIdx.x & 63;
  int t = wid;
  float2 a[16];
  a[0] = __half22float2(((const __half2*)(hws + (size_t)t * F))[lane]);
#pragma unroll
  for (int q = 1; q < 16; ++q) a[q] = make_float2(0.f, 0.f);
  int e0 = row_start[t], e1 = row_start[t + 1];
  int e = e0;
  for (; e + 16 <= e1; e += 16) {
#pragma unroll
    for (int q = 0; q < 16; ++q) {
      int s = csr_src[e + q];
      float2 v = __half22float2(((const __half2*)(hws + (size_t)s * F))[lane]);
      a[q].x += v.x;
      a[q].y += v.y;
    }
  }
  for (; e + 4 <= e1; e += 4) {
#pragma unroll
    for (int q = 0; q < 4; ++q) {
      int s = csr_src[e + q];
      float2 v = __half22float2(((const __half2*)(hws + (size_t)s * F))[lane]);
      a[q].x += v.x;
      a[q].y += v.y;
    }
  }
  for (; e < e1; ++e) {
    int s = csr_src[e];
    float2 v = __half22float2(((const __half2*)(hws + (size_t)s * F))[lane]);
    a[0].x += v.x; a[0].y += v.y;
  }
#pragma unroll
  for (int q = 0; q < 8; ++q) {
    a[q].x += a[q + 8].x;
    a[q].y += a[q + 8].y;
  }
  float d = dinv[t];
  float sx = ((a[0].x + a[1].x) + (a[2].x + a[3].x)) + ((a[4].x + a[5].x) + (a[6].x + a[7].x));
  float sy = ((a[0].y + a[1].y) + (a[2].y + a[3].y)) + ((a[4].y + a[5].y) + (a[6].y + a[7].y));
  float vx = sx * d + bias[lane * 2];
  float vy = sy * d + bias[lane * 2 + 1];
  uint32_t j = (uint32_t)t * 128u + (uint32_t)lane * 2u;
  vx = drop_keep(k0, k1, j)     ? fmaxf(vx * 1.25f, 0.f) : 0.f;
  vy = drop_keep(k0, k1, j + 1) ? fmaxf(vy * 1.25f, 0.f) : 0.f;
  __half2 o;
  o.x = __float2half_rn(vx);
  o.y = __float2half_rn(vy);
  out[(size_t)t * 64 + lane] = *(uint32_t*)&o;
}

// ------------------------- launch -------------------------
static inline size_t ws_align(size_t x) { return (x + 255) & ~(size_t)255; }

extern "C" void kernel_launch(void* const* d_in, const int* in_sizes, int n_in,
                              void* d_out, int out_size, void* d_ws, size_t ws_size,
                              hipStream_t stream) {
  const float* x  = (const float*)d_in[0];
  const float* W1 = (const float*)d_in[1];
  const float* b1 = (const float*)d_in[2];
  const float* W2 = (const float*)d_in[3];
  const float* b2 = (const float*)d_in[4];
  const float* W3 = (const float*)d_in[5];
  const float* b3 = (const float*)d_in[6];
  const int*   ei = (const int*)d_in[7];

  const int IN = 128, H2 = 256, HID = 128, OD = 64;
  const int n = in_sizes[0] / IN;   // 50000
  const int E = in_sizes[7] / 2;    // 800000
  const int* esrc = ei;
  const int* etgt = ei + E;
  const int nb = (n + 255) / 256;
  const int Mb128 = (n + 127) / 128;  // 391
  const int Mpad = Mb128 * 128;       // 50048
  const int grpRB = (Mb128 + 7) / 8;  // 49

  char* w = (char*)d_ws;
  size_t off = 0;
  auto alloc = [&](size_t bytes) { void* p = w + off; off += ws_align(bytes); return p; };
  float*    dinv      = (float*)alloc((size_t)n * 4);
  int*      cnt       = (int*)alloc((size_t)n * 4);
  int*      cursor    = (int*)alloc((size_t)n * 4);   // adjacent to cnt (one memset)
  int*      row_start = (int*)alloc(((size_t)n + 1) * 4);
  int*      bsum      = (int*)alloc(256 * 4);
  int*      bbase     = (int*)alloc(256 * 4);
  int*      csr_src   = (int*)alloc((size_t)E * 4);
  uint16_t* xs16      = (uint16_t*)alloc((size_t)n * IN * 2);
  uint16_t* A1        = (uint16_t*)alloc((size_t)Mpad * IN * 2);   // ag / h2 (f16, aliased)
  uint16_t* h1_16     = (uint16_t*)alloc((size_t)Mpad * H2 * 2);   // h1 f16
  uint16_t* hw2_16    = (uint16_t*)alloc((size_t)n * HID * 2);
  uint64_t* mask1     = (uint64_t*)alloc((size_t)n * 4 * 8);
  uint16_t* Wt1h      = (uint16_t*)alloc((size_t)H2 * IN * 2);
  uint16_t* Wt1l      = (uint16_t*)alloc((size_t)H2 * IN * 2);
  uint16_t* Wt2h      = (uint16_t*)alloc((size_t)HID * H2 * 2);
  uint16_t* Wt2l      = (uint16_t*)alloc((size_t)HID * H2 * 2);
  uint16_t* Wt3h      = (uint16_t*)alloc((size_t)OD * IN * 2);
  uint16_t* Wt3l      = (uint16_t*)alloc((size_t)OD * IN * 2);
  (void)ws_size;

  hipFuncSetAttribute((const void*)&k_mfma<2, 128>,
                      hipFuncAttributeMaxDynamicSharedMemorySize, 32768);
  hipFuncSetAttribute((const void*)&k_mfma<0, 256>,
                      hipFuncAttributeMaxDynamicSharedMemorySize, 65536);
  hipFuncSetAttribute((const void*)&k_mfma<1, 128>,
                      hipFuncAttributeMaxDynamicSharedMemorySize, 32768);

  uint32_t dk1_0, dk1_1, dk2_0, dk2_1;
  threefry2x32(0u, 42u, 0u, 0u, dk1_0, dk1_1);
  threefry2x32(0u, 42u, 0u, 1u, dk2_0, dk2_1);

  // single memset covers cnt + cursor (adjacent allocations)
  hipMemsetAsync(cnt, 0, ws_align((size_t)n * 4) + (size_t)n * 4, stream);

  k_cvtW3<<<(256 * 128 + 128 * 256 + 64 * 128 + 255) / 256, 256, 0, stream>>>(
      W1, Wt1h, Wt1l, W2, Wt2h, Wt2l, W3, Wt3h, Wt3l);

  k_hist<<<(E + 255) / 256, 256, 0, stream>>>(etgt, cnt, E);
  k_scan1<<<nb, 256, 0, stream>>>(cnt, row_start, bsum, dinv, n);
  k_scan2<<<1, 256, 0, stream>>>(bsum, bbase, row_start, nb, n);
  k_scan3<<<nb, 256, 0, stream>>>(row_start, bbase, n);
  k_scatter<<<(E + 255) / 256, 256, 0, stream>>>(esrc, etgt, row_start, cursor, csr_src, E);

  // layer 1
  int total2 = n * IN / 2;
  k_scale16<<<(total2 + 255) / 256, 256, 0, stream>>>(x, dinv, xs16, total2);
  k_agg_x<<<(n + 3) / 4, 256, 0, stream>>>(xs16, dinv, row_start, csr_src,
                                           (uint32_t*)A1, mask1, dk1_0, dk1_1, n);
  k_mfma<2, 128><<<grpRB * 8 * 4, 256, 32768, stream>>>(A1, Wt1h, Wt1l, b1, nullptr,
                                                        h1_16, mask1, n, H2, 4, Mb128);

  // layer 2
  k_mfma<0, 256><<<grpRB * 8 * 2, 256, 65536, stream>>>(h1_16, Wt2h, Wt2l, dinv, nullptr,
                                                        hw2_16, nullptr, n, HID, 2, Mb128);
  k_agg_w<<<(n + 3) / 4, 256, 0, stream>>>(hw2_16, dinv, b2, row_start, csr_src,
                                           (uint32_t*)A1, dk2_0, dk2_1, n);

  // layer 3
  k_mfma<1, 128><<<grpRB * 8, 256, 32768, stream>>>(A1, Wt3h, Wt3l, b3, (float*)d_out,
                                                    nullptr, nullptr, n, OD, 1, Mb128);
}

// Round 17
// 257.981 us; speedup vs baseline: 1.0630x; 1.0630x over previous
//
#include <hip/hip_runtime.h>
#include <hip/hip_fp16.h>
#include <stdint.h>

// ---------------------------------------------------------------------------
// GCN 3-layer forward, MI355X. Round 17 (= r14 exactly, plus risk-free scraps):
//  - agg kernels byte-identical to r14 (8-wide MLP, VGPR 28, occ 64% sweet
//    spot; r16's 16-wide raised VGPR->48, occ 42%, REGRESSED).
//  - PRNG placement = r14 (best of 4 tested): mask1 ballots in agg_x,
//    inline threefry in agg_w. Integer-form compare (bit-identical).
//  - launch graph 13 -> 11 nodes: scan2+scan3 merged (k_scanfix, redundant
//    per-block prefix over <=256 block sums); cvtW3 fused into scale16 (k_prep).
// ---------------------------------------------------------------------------

typedef __attribute__((ext_vector_type(8))) short s8v;   // 8 f16 (4 VGPR)
typedef __attribute__((ext_vector_type(4))) float f4v;   // 4 f32 acc

__device__ __host__ __forceinline__ uint32_t tf_rotl(uint32_t v, int r) {
  return (v << r) | (v >> (32 - r));
}

__device__ __host__ __forceinline__ void threefry2x32(uint32_t k0, uint32_t k1,
                                                      uint32_t x0, uint32_t x1,
                                                      uint32_t& o0, uint32_t& o1) {
  const uint32_t k2 = k0 ^ k1 ^ 0x1BD11BDAu;
  x0 += k0; x1 += k1;
#define TFR(r) { x0 += x1; x1 = tf_rotl(x1, r); x1 ^= x0; }
  TFR(13) TFR(15) TFR(26) TFR(6)
  x0 += k1; x1 += k2 + 1u;
  TFR(17) TFR(29) TFR(16) TFR(24)
  x0 += k2; x1 += k0 + 2u;
  TFR(13) TFR(15) TFR(26) TFR(6)
  x0 += k0; x1 += k1 + 3u;
  TFR(17) TFR(29) TFR(16) TFR(24)
  x0 += k1; x1 += k2 + 4u;
  TFR(13) TFR(15) TFR(26) TFR(6)
  x0 += k2; x1 += k0 + 5u;
#undef TFR
  o0 = x0; o1 = x1;
}

// keep <=> uniform(bits) < 0.8 ; exact integer form (bit-identical, verified
// r15/r16): u = bitcast(0x3f800000|(bits>>9)) - 1 < 0.8f <=> bits < 0xCCCCCE00
__device__ __forceinline__ bool drop_keep(uint32_t k0, uint32_t k1, uint32_t j) {
  uint32_t a, b;
  threefry2x32(k0, k1, 0u, j, a, b);
  return (a ^ b) < 0xCCCCCE00u;
}

// f16 hi / scaled-lo helper (weights only)
__device__ __forceinline__ void split16(float v, uint16_t& h, uint16_t& l) {
  __half hh = __float2half_rn(v);
  h = __half_as_ushort(hh);
  l = __half_as_ushort(__float2half_rn((v - __half2float(hh)) * 2048.0f));
}

// async global->LDS, 16B/lane; lds base wave-uniform (HW adds lane*16)
__device__ __forceinline__ void gll16(const void* g, void* l) {
  __builtin_amdgcn_global_load_lds(
      (const __attribute__((address_space(1))) uint32_t*)g,
      (__attribute__((address_space(3))) uint32_t*)l, 16, 0, 0);
}

// ------------------------- CSR build -------------------------
__global__ void k_hist(const int* __restrict__ tgt, int* __restrict__ cnt, int E) {
  int e = blockIdx.x * 256 + threadIdx.x;
  if (e < E) atomicAdd(&cnt[tgt[e]], 1);
}

__global__ __launch_bounds__(256) void k_scan1(const int* __restrict__ cnt,
                                               int* __restrict__ row_start,
                                               int* __restrict__ bsum,
                                               float* __restrict__ dinv, int n) {
  int tid = threadIdx.x;
  int i = blockIdx.x * 256 + tid;
  int c = (i < n) ? cnt[i] : 0;
  if (i < n) dinv[i] = rsqrtf((float)(c + 1));  // +1 self-loop
  int lane = tid & 63, wv = tid >> 6;
  int v = c;
#pragma unroll
  for (int d = 1; d < 64; d <<= 1) {
    int u = __shfl_up(v, d);
    if (lane >= d) v += u;
  }
  __shared__ int ws[4];
  if (lane == 63) ws[wv] = v;
  __syncthreads();
  int add = 0;
#pragma unroll
  for (int w = 0; w < 4; ++w)
    if (w < wv) add += ws[w];
  int incl = v + add;
  if (i < n) row_start[i] = incl - c;
  if (tid == 255) bsum[blockIdx.x] = incl;
}

// merged scan2+scan3: each block redundantly reduces its prefix of bsum
// (nb <= 256), adds to its 256 row_start entries; last block writes row_start[n].
__global__ __launch_bounds__(256) void k_scanfix(int* __restrict__ row_start,
                                                 const int* __restrict__ bsum,
                                                 int nb, int n) {
  int tid = threadIdx.x;
  int bid = blockIdx.x;
  int val = (tid < nb) ? bsum[tid] : 0;
  int pre = (tid < bid) ? val : 0;       // prefix sum contribution
  // block-wide reductions (two values) via shfl + LDS
  int lane = tid & 63, wv = tid >> 6;
  int a = pre, b = val;
#pragma unroll
  for (int d = 32; d > 0; d >>= 1) {
    a += __shfl_down(a, d);
    b += __shfl_down(b, d);
  }
  __shared__ int sa[4], sb2[4];
  if (lane == 0) { sa[wv] = a; sb2[wv] = b; }
  __syncthreads();
  __shared__ int base_s, tot_s;
  if (tid == 0) {
    base_s = sa[0] + sa[1] + sa[2] + sa[3];
    tot_s = sb2[0] + sb2[1] + sb2[2] + sb2[3];
  }
  __syncthreads();
  int i = bid * 256 + tid;
  if (i < n) row_start[i] += base_s;
  if (bid == nb - 1 && tid == 0) row_start[n] = tot_s;
}

__global__ void k_scatter(const int* __restrict__ src, const int* __restrict__ tgt,
                          const int* __restrict__ row_start, int* __restrict__ cursor,
                          int* __restrict__ csr_src, int E) {
  int e = blockIdx.x * 256 + threadIdx.x;
  if (e >= E) return;
  int t = tgt[e];
  int pos = atomicAdd(&cursor[t], 1);
  csr_src[row_start[t] + pos] = src[e];
}

// ------------------------- fused scale16 + weight-convert (k_prep) ----------------
// blocks [0, SB): xs16 = f16(x*dinv[row]);  blocks [SB, SB+384): cvtW3.
__global__ __launch_bounds__(256) void k_prep(const float* __restrict__ x,
                                              const float* __restrict__ dinv,
                                              uint16_t* __restrict__ xs, int total2, int SB,
                                              const float* __restrict__ W1, uint16_t* __restrict__ W1h,
                                              uint16_t* __restrict__ W1l,
                                              const float* __restrict__ W2, uint16_t* __restrict__ W2h,
                                              uint16_t* __restrict__ W2l,
                                              const float* __restrict__ W3, uint16_t* __restrict__ W3h,
                                              uint16_t* __restrict__ W3l) {
  int bid = blockIdx.x;
  if (bid < SB) {
    int i = bid * 256 + threadIdx.x;
    if (i >= total2) return;
    float2 v = ((const float2*)x)[i];
    float s = dinv[i >> 6];
    __half2 h;
    h.x = __float2half_rn(v.x * s);
    h.y = __float2half_rn(v.y * s);
    ((__half2*)xs)[i] = h;
    return;
  }
  const int T1 = 256 * 128, T2 = 128 * 256, T3 = 64 * 128;
  int i = (bid - SB) * 256 + threadIdx.x;
  if (i < T1) {
    int nn = i >> 7, kk = i & 127;                  // K=128, N=256
    split16(W1[(size_t)kk * 256 + nn], W1h[i], W1l[i]);
  } else if (i < T1 + T2) {
    int j = i - T1;
    int nn = j >> 8, kk = j & 255;                  // K=256, N=128
    split16(W2[(size_t)kk * 128 + nn], W2h[j], W2l[j]);
  } else if (i < T1 + T2 + T3) {
    int j = i - T1 - T2;
    int nn = j >> 7, kk = j & 127;                  // K=128, N=64
    split16(W3[(size_t)kk * 64 + nn], W3h[j], W3l[j]);
  }
}

// ------------------------- f16 MFMA GEMM, barrier-free, XCD-swizzled grid --------
// 1-D grid: xcd=id&7, ct=(id>>3)%CTN, rb=((id>>3)/CTN)*8+xcd (rb>=RB -> exit).
// Block: 4 waves, 128 rows x 64 cols. B tile (64 cols x K, hi+lo') in LDS once;
// A fragments (single f16) global->reg once. 2 MFMA passes: Ah*Bh, Ah*Bl.
// MODE 0: C16=f16(v*sb[row]);  MODE 1: Cf=v+sb[col];  MODE 2: C16=f16(relu(mask?v*1.25:0))
template <int MODE, int K>
__global__ __launch_bounds__(256, K == 128 ? 4 : 2) void k_mfma(
    const uint16_t* __restrict__ Ah,
    const uint16_t* __restrict__ Bh, const uint16_t* __restrict__ Bl,
    const float* __restrict__ sb, float* __restrict__ Cf,
    uint16_t* __restrict__ C16, const uint64_t* __restrict__ mask,
    int M, int N, int CTN, int RB) {
  constexpr int SEGS = K / 8;
  constexpr int CHT = 64 * SEGS;         // 16B chunks per B array
  constexpr int KS = K / 32;
  extern __shared__ uint16_t lB[];       // hi CHT*8, lo CHT*8

  int id = blockIdx.x;
  int xcd = id & 7;
  int q = id >> 3;
  int ct = q % CTN;
  int rb = (q / CTN) * 8 + xcd;
  if (rb >= RB) return;

  int tid = threadIdx.x;
  int lane = tid & 63;
  int wid = tid >> 6;
  int r16 = lane & 15, kq = lane >> 4;
  int bm = rb * 128, bn0 = ct * 64;

  // ---- stage B tile (hi + lo') once ----
#pragma unroll
  for (int p = 0; p < (2 * CHT) / 256; ++p) {
    int c = p * 256 + tid;
    int arr = (c >= CHT);
    int cc = arr ? c - CHT : c;
    int row = cc / SEGS, u = cc - row * SEGS;
    int seg = u ^ (row & 7);  // inverse-swizzled source
    const uint16_t* src = (arr ? Bl : Bh) + (size_t)(bn0 + row) * K + seg * 8;
    gll16(src, lB + (size_t)(p * 256 + (wid << 6)) * 8);
  }

  // ---- load A fragments once (overlaps B staging latency) ----
  int mrow0 = bm + wid * 32;
  s8v aH[2][KS];
#pragma unroll
  for (int mb = 0; mb < 2; ++mb)
#pragma unroll
    for (int ks = 0; ks < KS; ++ks) {
      size_t ga = (size_t)(mrow0 + mb * 16 + r16) * K + ks * 32 + kq * 8;
      aH[mb][ks] = *(const s8v*)&Ah[ga];
    }

  asm volatile("s_waitcnt vmcnt(0)" ::: "memory");
  __syncthreads();

  const uint16_t* tbh = lB;
  const uint16_t* tbl = lB + (size_t)CHT * 8;
  f4v accH[2][4] = {};
  f4v accL[2][4] = {};
#pragma unroll
  for (int ks = 0; ks < KS; ++ks) {
    s8v bh[4], bl[4];
#pragma unroll
    for (int nb = 0; nb < 4; ++nb) {
      int brow = nb * 16 + r16;
      int u = (ks * 4 + kq) ^ (brow & 7);
      bh[nb] = *(const s8v*)&tbh[brow * K + u * 8];
      bl[nb] = *(const s8v*)&tbl[brow * K + u * 8];
    }
#pragma unroll
    for (int mb = 0; mb < 2; ++mb) {
#pragma unroll
      for (int nb = 0; nb < 4; ++nb) {
        accH[mb][nb] = __builtin_amdgcn_mfma_f32_16x16x32_f16(aH[mb][ks], bh[nb], accH[mb][nb], 0, 0, 0);
        accL[mb][nb] = __builtin_amdgcn_mfma_f32_16x16x32_f16(aH[mb][ks], bl[nb], accL[mb][nb], 0, 0, 0);
      }
    }
  }

  // ---- epilogue ----
#pragma unroll
  for (int mb = 0; mb < 2; ++mb) {
#pragma unroll
    for (int nb = 0; nb < 4; ++nb) {
      int col = bn0 + nb * 16 + r16;
#pragma unroll
      for (int r = 0; r < 4; ++r) {
        int row = mrow0 + mb * 16 + kq * 4 + r;
        if (row >= M) continue;
        float v = accH[mb][nb][r] + accL[mb][nb][r] * (1.0f / 2048.0f);
        size_t o = (size_t)row * N + col;
        if (MODE == 0) {
          C16[o] = __half_as_ushort(__float2half_rn(v * sb[row]));
        } else if (MODE == 1) {
          Cf[o] = v + sb[col];
        } else {
          v += sb[col];
          uint64_t m = mask[(size_t)row * (N >> 6) + (col >> 6)];
          v = ((m >> (col & 63)) & 1ull) ? fmaxf(v * 1.25f, 0.f) : 0.f;
          C16[o] = __half_as_ushort(__float2half_rn(v));
        }
      }
    }
  }
}

// ------------------------- layer-1 aggregation (MLP-8) + mask1 ballots ------------
__global__ __launch_bounds__(256) void k_agg_x(const uint16_t* __restrict__ xs,
                                               const float* __restrict__ dinv,
                                               const int* __restrict__ row_start,
                                               const int* __restrict__ csr_src,
                                               uint32_t* __restrict__ out,
                                               uint64_t* __restrict__ mask1,
                                               uint32_t k0, uint32_t k1, int n) {
  const int F = 128;
  int wid = (int)((blockIdx.x * 256 + threadIdx.x) >> 6);
  if (wid >= n) return;
  int lane = threadIdx.x & 63;
  int t = wid;
  float2 a[8];
  a[0] = __half22float2(((const __half2*)(xs + (size_t)t * F))[lane]);
#pragma unroll
  for (int q = 1; q < 8; ++q) a[q] = make_float2(0.f, 0.f);
  int e0 = row_start[t], e1 = row_start[t + 1];
  int e = e0;
  for (; e + 8 <= e1; e += 8) {
#pragma unroll
    for (int q = 0; q < 8; ++q) {
      int s = csr_src[e + q];
      float2 v = __half22float2(((const __half2*)(xs + (size_t)s * F))[lane]);
      a[q].x += v.x;
      a[q].y += v.y;
    }
  }
  for (; e < e1; ++e) {
    int s = csr_src[e];
    float2 v = __half22float2(((const __half2*)(xs + (size_t)s * F))[lane]);
    a[0].x += v.x; a[0].y += v.y;
  }
  float dt = dinv[t];
  float rx = (((a[0].x + a[1].x) + (a[2].x + a[3].x)) + ((a[4].x + a[5].x) + (a[6].x + a[7].x))) * dt;
  float ry = (((a[0].y + a[1].y) + (a[2].y + a[3].y)) + ((a[4].y + a[5].y) + (a[6].y + a[7].y))) * dt;
  __half2 o;
  o.x = __float2half_rn(rx);
  o.y = __float2half_rn(ry);
  out[(size_t)t * 64 + lane] = *(uint32_t*)&o;
  // layer-1 dropout mask (hidden under gather latency): elem j = t*256 + w*64 + lane
#pragma unroll
  for (int w = 0; w < 4; ++w) {
    bool kp = drop_keep(k0, k1, (uint32_t)t * 256u + (uint32_t)(w * 64 + lane));
    uint64_t m = __ballot(kp);
    if (lane == 0) mask1[(size_t)t * 4 + w] = m;
  }
}

// ------------------------- layer-2 aggregation + bias + inline-drop + relu --------
__global__ __launch_bounds__(256) void k_agg_w(const uint16_t* __restrict__ hws,
                                               const float* __restrict__ dinv,
                                               const float* __restrict__ bias,
                                               const int* __restrict__ row_start,
                                               const int* __restrict__ csr_src,
                                               uint32_t* __restrict__ out,
                                               uint32_t k0, uint32_t k1, int n) {
  const int F = 128;
  int wid = (int)((blockIdx.x * 256 + threadIdx.x) >> 6);
  if (wid >= n) return;
  int lane = threadIdx.x & 63;
  int t = wid;
  float2 a[8];
  a[0] = __half22float2(((const __half2*)(hws + (size_t)t * F))[lane]);
#pragma unroll
  for (int q = 1; q < 8; ++q) a[q] = make_float2(0.f, 0.f);
  int e0 = row_start[t], e1 = row_start[t + 1];
  int e = e0;
  for (; e + 8 <= e1; e += 8) {
#pragma unroll
    for (int q = 0; q < 8; ++q) {
      int s = csr_src[e + q];
      float2 v = __half22float2(((const __half2*)(hws + (size_t)s * F))[lane]);
      a[q].x += v.x;
      a[q].y += v.y;
    }
  }
  for (; e < e1; ++e) {
    int s = csr_src[e];
    float2 v = __half22float2(((const __half2*)(hws + (size_t)s * F))[lane]);
    a[0].x += v.x; a[0].y += v.y;
  }
  float d = dinv[t];
  float sx = ((a[0].x + a[1].x) + (a[2].x + a[3].x)) + ((a[4].x + a[5].x) + (a[6].x + a[7].x));
  float sy = ((a[0].y + a[1].y) + (a[2].y + a[3].y)) + ((a[4].y + a[5].y) + (a[6].y + a[7].y));
  float vx = sx * d + bias[lane * 2];
  float vy = sy * d + bias[lane * 2 + 1];
  uint32_t j = (uint32_t)t * 128u + (uint32_t)lane * 2u;
  vx = drop_keep(k0, k1, j)     ? fmaxf(vx * 1.25f, 0.f) : 0.f;
  vy = drop_keep(k0, k1, j + 1) ? fmaxf(vy * 1.25f, 0.f) : 0.f;
  __half2 o;
  o.x = __float2half_rn(vx);
  o.y = __float2half_rn(vy);
  out[(size_t)t * 64 + lane] = *(uint32_t*)&o;
}

// ------------------------- launch -------------------------
static inline size_t ws_align(size_t x) { return (x + 255) & ~(size_t)255; }

extern "C" void kernel_launch(void* const* d_in, const int* in_sizes, int n_in,
                              void* d_out, int out_size, void* d_ws, size_t ws_size,
                              hipStream_t stream) {
  const float* x  = (const float*)d_in[0];
  const float* W1 = (const float*)d_in[1];
  const float* b1 = (const float*)d_in[2];
  const float* W2 = (const float*)d_in[3];
  const float* b2 = (const float*)d_in[4];
  const float* W3 = (const float*)d_in[5];
  const float* b3 = (const float*)d_in[6];
  const int*   ei = (const int*)d_in[7];

  const int IN = 128, H2 = 256, HID = 128, OD = 64;
  const int n = in_sizes[0] / IN;   // 50000
  const int E = in_sizes[7] / 2;    // 800000
  const int* esrc = ei;
  const int* etgt = ei + E;
  const int nb = (n + 255) / 256;     // 196 (<= 256 required by k_scanfix)
  const int Mb128 = (n + 127) / 128;  // 391
  const int Mpad = Mb128 * 128;       // 50048
  const int grpRB = (Mb128 + 7) / 8;  // 49

  char* w = (char*)d_ws;
  size_t off = 0;
  auto alloc = [&](size_t bytes) { void* p = w + off; off += ws_align(bytes); return p; };
  float*    dinv      = (float*)alloc((size_t)n * 4);
  int*      cnt       = (int*)alloc((size_t)n * 4);
  int*      cursor    = (int*)alloc((size_t)n * 4);   // adjacent to cnt (one memset)
  int*      row_start = (int*)alloc(((size_t)n + 1) * 4);
  int*      bsum      = (int*)alloc(256 * 4);
  int*      csr_src   = (int*)alloc((size_t)E * 4);
  uint16_t* xs16      = (uint16_t*)alloc((size_t)n * IN * 2);
  uint16_t* A1        = (uint16_t*)alloc((size_t)Mpad * IN * 2);   // ag / h2 (f16, aliased)
  uint16_t* h1_16     = (uint16_t*)alloc((size_t)Mpad * H2 * 2);   // h1 f16
  uint16_t* hw2_16    = (uint16_t*)alloc((size_t)n * HID * 2);
  uint64_t* mask1     = (uint64_t*)alloc((size_t)n * 4 * 8);
  uint16_t* Wt1h      = (uint16_t*)alloc((size_t)H2 * IN * 2);
  uint16_t* Wt1l      = (uint16_t*)alloc((size_t)H2 * IN * 2);
  uint16_t* Wt2h      = (uint16_t*)alloc((size_t)HID * H2 * 2);
  uint16_t* Wt2l      = (uint16_t*)alloc((size_t)HID * H2 * 2);
  uint16_t* Wt3h      = (uint16_t*)alloc((size_t)OD * IN * 2);
  uint16_t* Wt3l      = (uint16_t*)alloc((size_t)OD * IN * 2);
  (void)ws_size;

  hipFuncSetAttribute((const void*)&k_mfma<2, 128>,
                      hipFuncAttributeMaxDynamicSharedMemorySize, 32768);
  hipFuncSetAttribute((const void*)&k_mfma<0, 256>,
                      hipFuncAttributeMaxDynamicSharedMemorySize, 65536);
  hipFuncSetAttribute((const void*)&k_mfma<1, 128>,
                      hipFuncAttributeMaxDynamicSharedMemorySize, 32768);

  uint32_t dk1_0, dk1_1, dk2_0, dk2_1;
  threefry2x32(0u, 42u, 0u, 0u, dk1_0, dk1_1);
  threefry2x32(0u, 42u, 0u, 1u, dk2_0, dk2_1);

  // single memset covers cnt + cursor (adjacent allocations)
  hipMemsetAsync(cnt, 0, ws_align((size_t)n * 4) + (size_t)n * 4, stream);

  // CSR
  k_hist<<<(E + 255) / 256, 256, 0, stream>>>(etgt, cnt, E);
  k_scan1<<<nb, 256, 0, stream>>>(cnt, row_start, bsum, dinv, n);
  k_scanfix<<<nb, 256, 0, stream>>>(row_start, bsum, nb, n);
  k_scatter<<<(E + 255) / 256, 256, 0, stream>>>(esrc, etgt, row_start, cursor, csr_src, E);

  // prep: xs16 (needs dinv) + weight convert, one kernel
  int total2 = n * IN / 2;
  int SB = (total2 + 255) / 256;
  k_prep<<<SB + (256 * 128 + 128 * 256 + 64 * 128 + 255) / 256, 256, 0, stream>>>(
      x, dinv, xs16, total2, SB,
      W1, Wt1h, Wt1l, W2, Wt2h, Wt2l, W3, Wt3h, Wt3l);

  // layer 1
  k_agg_x<<<(n + 3) / 4, 256, 0, stream>>>(xs16, dinv, row_start, csr_src,
                                           (uint32_t*)A1, mask1, dk1_0, dk1_1, n);
  k_mfma<2, 128><<<grpRB * 8 * 4, 256, 32768, stream>>>(A1, Wt1h, Wt1l, b1, nullptr,
                                                        h1_16, mask1, n, H2, 4, Mb128);

  // layer 2
  k_mfma<0, 256><<<grpRB * 8 * 2, 256, 65536, stream>>>(h1_16, Wt2h, Wt2l, dinv, nullptr,
                                                        hw2_16, nullptr, n, HID, 2, Mb128);
  k_agg_w<<<(n + 3) / 4, 256, 0, stream>>>(hw2_16, dinv, b2, row_start, csr_src,
                                           (uint32_t*)A1, dk2_0, dk2_1, n);

  // layer 3
  k_mfma<1, 128><<<grpRB * 8, 256, 32768, stream>>>(A1, Wt3h, Wt3l, b3, (float*)d_out,
                                                    nullptr, nullptr, n, OD, 1, Mb128);
}